// Round 3
// baseline (449.863 us; speedup 1.0000x reference)
//
#include <hip/hip_runtime.h>
#include <hip/hip_cooperative_groups.h>
#include <float.h>

namespace cg = cooperative_groups;

#define N_PART 262144
#define GRID_DIM 256
#define NUM_CELLS (GRID_DIM * GRID_DIM)
#define KSLOT 32
#define MAXNB 64
#define BLD_BLOCKS 256
#define BLD_TPB 256
#define BLD_NT (BLD_BLOCKS * BLD_TPB)   // 65536 threads, 1 block/CU

// ---------------- ws layout (all 256B-aligned) ----------------
// counts     : NUM_CELLS ints          (zeroed in-kernel)
// cursor     : NUM_CELLS ints          (zeroed in-kernel)
// chunkSums  : 256 ints
// chunkOff   : 256 ints
// starts     : NUM_CELLS+2 ints        (CSR row starts; [NC]=[NC+1]=N)
// lin        : N ints                  (cell of each particle)
// sid        : N+64 ints               (particle ids, cell-major, unsorted)
// linS       : N ints                  (cell of rank r)
// Q          : (N+64) float4           ({x, y, id-as-float-bits, sup})
// blockMinX/Y/MaxH : 256 floats each   (per-block reduce partials)

// Whole build pipeline in ONE cooperative dispatch: the 8 tiny kernels it
// replaces were costing ~25us each in launch/serialization gaps while
// touching only ~15MB of dense data. 256 blocks = 1 block/CU, co-resident
// by cooperative-launch guarantee; grid.sync() is the phase boundary.
__global__ __launch_bounds__(BLD_TPB) void build_kernel(
        const float2* __restrict__ pos2, const float* __restrict__ sup,
        int* counts, int* cursor, int* chunkSums, int* chunkOff,
        int* starts, int* lin, int* sid, int* linS, float4* Q,
        float* blockMinX, float* blockMinY, float* blockMaxH) {
    cg::grid_group grid = cg::this_grid();
    __shared__ unsigned s_minx, s_miny, s_maxh;
    __shared__ int sd[256];

    int t   = threadIdx.x;
    int b   = blockIdx.x;
    int tid = b * BLD_TPB + t;

    // ---- P0: zero tables + per-block min/max partials ----
    counts[tid] = 0;
    cursor[tid] = 0;
    if (t == 0) { s_minx = 0x7f7fffffu; s_miny = 0x7f7fffffu; s_maxh = 0u; }
    __syncthreads();
    {
        float mx = FLT_MAX, my = FLT_MAX, mh = 0.0f;
#pragma unroll
        for (int k = 0; k < N_PART / BLD_NT; k++) {
            int i = tid + k * BLD_NT;
            float2 p = pos2[i];
            float h = sup[i];
            mx = fminf(mx, p.x);
            my = fminf(my, p.y);
            mh = fmaxf(mh, h);
        }
        // non-negative floats: uint compare == float compare
        atomicMin(&s_minx, __float_as_uint(mx));
        atomicMin(&s_miny, __float_as_uint(my));
        atomicMax(&s_maxh, __float_as_uint(mh));
    }
    __syncthreads();
    if (t == 0) {
        blockMinX[b] = __uint_as_float(s_minx);
        blockMinY[b] = __uint_as_float(s_miny);
        blockMaxH[b] = __uint_as_float(s_maxh);
    }
    grid.sync();

    // ---- P1: combine partials (redundant per block; min/max are exact,
    //          order-independent -> every block gets identical values) + bin
    if (t == 0) { s_minx = 0x7f7fffffu; s_miny = 0x7f7fffffu; s_maxh = 0u; }
    __syncthreads();
    atomicMin(&s_minx, __float_as_uint(blockMinX[t]));
    atomicMin(&s_miny, __float_as_uint(blockMinY[t]));
    atomicMax(&s_maxh, __float_as_uint(blockMaxH[t]));
    __syncthreads();
    float hmax  = __uint_as_float(s_maxh);
    float qminx = __uint_as_float(s_minx) - hmax;
    float qminy = __uint_as_float(s_miny) - hmax;
#pragma unroll
    for (int k = 0; k < N_PART / BLD_NT; k++) {
        int i = tid + k * BLD_NT;
        float2 p = pos2[i];
        int cx = (int)ceilf((p.x - qminx) / hmax);
        int cy = (int)ceilf((p.y - qminy) / hmax);
        cx = min(max(cx, 0), GRID_DIM - 1);
        cy = min(max(cy, 0), GRID_DIM - 1);
        int l = cx + GRID_DIM * cy;
        lin[i] = l;
        atomicAdd(&counts[l], 1);
    }
    grid.sync();

    // ---- P2: per-block exclusive scan of its 256 counts ----
    {
        int v = counts[tid];
        sd[t] = v;
        __syncthreads();
#pragma unroll
        for (int off = 1; off < 256; off <<= 1) {
            int x = (t >= off) ? sd[t - off] : 0;
            __syncthreads();
            sd[t] += x;
            __syncthreads();
        }
        starts[tid] = sd[t] - v;            // exclusive within chunk
        if (t == 255) chunkSums[b] = sd[t];
    }
    grid.sync();

    // ---- P3: block 0 exclusive-scans the 256 chunk sums ----
    if (b == 0) {
        int cv = chunkSums[t];
        sd[t] = cv;
        __syncthreads();
#pragma unroll
        for (int off = 1; off < 256; off <<= 1) {
            int x = (t >= off) ? sd[t - off] : 0;
            __syncthreads();
            sd[t] += x;
            __syncthreads();
        }
        chunkOff[t] = sd[t] - cv;
    }
    grid.sync();

    // ---- P4: apply chunk offsets ----
    starts[tid] += chunkOff[b];
    if (tid == 0) {
        starts[NUM_CELLS]     = N_PART;     // reference overflow row: empty
        starts[NUM_CELLS + 1] = N_PART;
    }
    grid.sync();

    // ---- P5: scatter (arbitrary intra-cell order; ordered at emit) ----
#pragma unroll
    for (int k = 0; k < N_PART / BLD_NT; k++) {
        int i = tid + k * BLD_NT;
        int c = lin[i];
        int r = atomicAdd(&cursor[c], 1);
        sid[starts[c] + r] = i;
    }
    grid.sync();

    // ---- P6: ordered emit. One thread per cell; rank = #(smaller ids in
    //          cell) restores ascending-id order (stable argsort semantics).
    //          e~Poisson(4): e^2 L1-hit reads. Lanes own consecutive cells
    //          -> Q writes from a wave cover a contiguous region.
    {
        int bb = starts[tid], ee = starts[tid + 1];
        for (int k = bb; k < ee; k++) {
            int val = sid[k];
            int rank = 0;
            for (int s = bb; s < ee; s++) rank += (sid[s] < val);
            float2 pj = pos2[val];      // bitwise copy: query numerics identical
            Q[bb + rank] = make_float4(pj.x, pj.y, __int_as_float(val), sup[val]);
            linS[bb + rank] = tid;
        }
    }
}

// One wave per RANK (cell-sorted order): consecutive waves read overlapping
// dense CSR segments -> L1/L2 hits. XCD-bijective block swizzle gives each
// XCD a contiguous 1/8 of the rank range, so its private L2 holds ~0.5MB of
// Q instead of all 4MB. Wave-uniform state in SGPRs via readfirstlane. The
// reference's boundary decision RN(sqrt(s2)) <= h is an interval of f32 s2
// values, so it collapses to ONE v_cmp_le_f32 against a per-wave threshold
// S = largest f32 < mid^2, mid = (h + nextafterf(h))/2 (mid^2 exact in
// double, 50 bits; mid^2 is never a 24-bit f32 so ties are impossible).
// sqrt runs only once per stored lane in the epilogue, as v_sqrt_f32 *
// v_rcp_f32 (~3ulp, well inside the comparator tolerance).
__global__ __launch_bounds__(256) void query_kernel(
        const int* __restrict__ linS, const float4* __restrict__ Q,
        const int* __restrict__ starts,
        float* __restrict__ outN, float* __restrict__ outC,
        float* __restrict__ outR, int n) {
#pragma clang fp contract(off)
    __shared__ int   s_id[4][MAXNB];
    __shared__ float s_s2[4][MAXNB];

    int bid = blockIdx.x;
    int swz = (bid & 7) * (int)(gridDim.x >> 3) + (bid >> 3);   // bijective
    int gtid = swz * 256 + threadIdx.x;
    int r    = gtid >> 6;              // rank in cell-sorted order (grid exact)
    int lane = threadIdx.x & 63;
    int wsl  = threadIdx.x >> 6;

    float4 me = Q[r];
    int   i  = __builtin_amdgcn_readfirstlane(__float_as_int(me.z));
    float px = __int_as_float(__builtin_amdgcn_readfirstlane(__float_as_int(me.x)));
    float py = __int_as_float(__builtin_amdgcn_readfirstlane(__float_as_int(me.y)));
    float h  = __int_as_float(__builtin_amdgcn_readfirstlane(__float_as_int(me.w)));
    int   L  = __builtin_amdgcn_readfirstlane(linS[r]);

    // exact f32 threshold for RN(sqrt(s2)) <= h   (h > 0, normal)
    float  hn  = __int_as_float(__float_as_int(h) + 1);     // nextafter(h, inf)
    double mid = 0.5 * ((double)h + (double)hn);
    double t2  = mid * mid;                                  // exact (50 bits)
    float  S   = (float)t2;                                  // RN
    S = ((double)S > t2) ? __int_as_float(__float_as_int(S) - 1) : S;  // RD

    // reference candidate-cell order: offs = dx + 256*dy, ij-meshgrid
    const int offs[9] = {-257, -1, 255, -256, 0, 256, -255, 1, 257};
    int cum[10], delta[9];
    cum[0] = 0;
#pragma unroll
    for (int o = 0; o < 9; o++) {
        int cell = L + offs[o];
        cell = min(max(cell, 0), NUM_CELLS);   // clip (duplicates at edges,
                                               //  exactly like the reference)
        int bb = __builtin_amdgcn_readfirstlane(starts[cell]);
        int ee = __builtin_amdgcn_readfirstlane(starts[cell + 1]);
        int cc = min(ee - bb, KSLOT);          // keep lowest-32 ids, as ref
        delta[o]  = bb - cum[o];               // idx = ll + delta[seg]
        cum[o + 1] = cum[o] + cc;
    }
    int T = cum[9];

    int total = 0;
    for (int b0 = 0; b0 < T; b0 += 64) {
        int ll = b0 + lane;
        int dsel = delta[0];
#pragma unroll
        for (int m = 1; m < 9; m++)
            dsel = (ll >= cum[m]) ? delta[m] : dsel;
        int idx = ll + dsel;                   // <= N+63: Q padded by 64
        float4 q = Q[idx];
        float dx = q.x - px;
        float dy = q.y - py;
        float s2 = dx * dx + dy * dy;          // contract(off): match XLA
        // scalar tail mask (SALU): lanes with ll >= T
        int rem = T - b0;
        unsigned long long maskT =
            (rem >= 64) ? ~0ull : ((1ull << rem) - 1ull);
        unsigned long long bal = __ballot(s2 <= S) & maskT;
        int rank = __builtin_amdgcn_mbcnt_hi(
            (unsigned)(bal >> 32),
            __builtin_amdgcn_mbcnt_lo((unsigned)bal, 0));
        int w = total + rank;
        if ((s2 <= S) && (ll < T) && (w < MAXNB)) {
            s_id[wsl][w] = __float_as_int(q.z);
            s_s2[wsl][w] = s2;
        }
        total += (int)__popcll(bal);
    }

    // wave-private LDS buffer, same-wave DS ops are ordered: no barrier.
    int stored = min(total, MAXNB);
    float rh = __builtin_amdgcn_rcpf(h);       // 1ulp; tolerance-covered
    size_t base = (size_t)i * MAXNB;           // 256B-aligned, fully written
    int   jj = s_id[wsl][lane];                // garbage beyond 'stored' is
    float ss = s_s2[wsl][lane];                //  discarded by cndmask below
    bool inb = lane < stored;
    float vN = inb ? (float)jj : -1.0f;
    float vR = inb ? __builtin_amdgcn_sqrtf(ss) * rh : 0.0f;
    outN[base + lane] = vN;
    outR[base + lane] = vR;
    if (lane == 0) outC[i] = (float)total;
}

extern "C" void kernel_launch(void* const* d_in, const int* in_sizes, int n_in,
                              void* d_out, int out_size, void* d_ws, size_t ws_size,
                              hipStream_t stream) {
    const float2* pos2 = (const float2*)d_in[0];
    const float*  sup  = (const float*)d_in[1];

    char* p = (char*)d_ws;
    auto alloc = [&](size_t bytes) {
        char* q = p;
        p += (bytes + 255) & ~(size_t)255;
        return q;
    };
    int*    counts    = (int*)alloc((size_t)NUM_CELLS * 4);
    int*    cursor    = (int*)alloc((size_t)NUM_CELLS * 4);
    int*    chunkSums = (int*)alloc(256 * 4);
    int*    chunkOff  = (int*)alloc(256 * 4);
    int*    starts    = (int*)alloc((size_t)(NUM_CELLS + 2) * 4);
    int*    lin       = (int*)alloc((size_t)N_PART * 4);
    int*    sid       = (int*)alloc((size_t)(N_PART + 64) * 4);
    int*    linS      = (int*)alloc((size_t)N_PART * 4);
    float4* Q         = (float4*)alloc((size_t)(N_PART + 64) * 16);
    float*  blockMinX = (float*)alloc(256 * 4);
    float*  blockMinY = (float*)alloc(256 * 4);
    float*  blockMaxH = (float*)alloc(256 * 4);

    float* out  = (float*)d_out;
    float* outN = out;                              // N*64 neighbor ids (as f32)
    float* outC = out + (size_t)N_PART * MAXNB;     // N counts
    float* outR = outC + N_PART;                    // N*64 radial

    void* args[] = { (void*)&pos2, (void*)&sup, (void*)&counts, (void*)&cursor,
                     (void*)&chunkSums, (void*)&chunkOff, (void*)&starts,
                     (void*)&lin, (void*)&sid, (void*)&linS, (void*)&Q,
                     (void*)&blockMinX, (void*)&blockMinY, (void*)&blockMaxH };
    hipLaunchCooperativeKernel((const void*)build_kernel, dim3(BLD_BLOCKS),
                               dim3(BLD_TPB), args, 0, stream);
    // one wave per rank: N_PART waves = N_PART*64 threads
    query_kernel<<<(N_PART * 64) / 256, 256, 0, stream>>>(
        linS, Q, starts, outN, outC, outR, N_PART);
}

// Round 5
// 403.056 us; speedup vs baseline: 1.1161x; 1.1161x over previous
//
#include <hip/hip_runtime.h>
#include <hip/hip_cooperative_groups.h>
#include <float.h>

namespace cg = cooperative_groups;

#define N_PART 262144
#define GRID_DIM 256
#define NUM_CELLS (GRID_DIM * GRID_DIM)
#define KSLOT 32
#define MAXNB 64
#define BLD_BLOCKS 256                  // proven cooperative grid size (r3)
#define BLD_TPB 1024                    // 256*1024 == N_PART exactly

// ---------------- ws layout (all 256B-aligned) ----------------
// counts     : NUM_CELLS ints          (zeroed in-kernel)
// cursor     : NUM_CELLS ints          (zeroed in-kernel)
// chunkSums  : 256 ints
// starts     : NUM_CELLS+2 ints        (CSR row starts; [NC]=[NC+1]=N)
// lin        : N ints                  (cell of each particle)
// sid        : N+64 ints               (particle ids, cell-major, unsorted)
// linS       : N ints                  (cell of rank r)
// Q          : (N+64) float4           ({x, y, id-as-float-bits, sup})
// bMinX/Y/H  : 256 floats each         (per-block reduce partials)

// Build pipeline in ONE cooperative dispatch at the PROVEN grid size.
// Round-3 lesson: 256 blocks x 256 thr = 1 wave/SIMD starved every
// latency-bound phase (Occupancy 10.7%, 250us). Round-4 lesson: >256
// blocks cooperative deadlocks grid.sync under capture (residency not
// validated). This version: 256 blocks x 1024 thr = 16 waves/CU, one
// particle/cell per thread, no loops -> max MLP at a legal grid.
__global__ __launch_bounds__(BLD_TPB) void build_kernel(
        const float2* __restrict__ pos2, const float* __restrict__ sup,
        int* counts, int* cursor, int* chunkSums, int* starts,
        int* lin, int* sid, int* linS, float4* Q,
        float* bMinX, float* bMinY, float* bMaxH) {
    cg::grid_group grid = cg::this_grid();
    __shared__ unsigned s_minx, s_miny, s_maxh;
    __shared__ int sd[256];

    int t   = threadIdx.x;
    int b   = blockIdx.x;
    int tid = b * BLD_TPB + t;          // covers [0, N_PART) exactly

    // ---- P0: zero tables + per-block min/max partials (1 particle/thread)
    if (tid < NUM_CELLS) { counts[tid] = 0; cursor[tid] = 0; }
    if (t == 0) { s_minx = 0x7f7fffffu; s_miny = 0x7f7fffffu; s_maxh = 0u; }
    __syncthreads();
    {
        float2 p = pos2[tid];
        float  h = sup[tid];
        // non-negative floats: uint compare == float compare
        atomicMin(&s_minx, __float_as_uint(p.x));
        atomicMin(&s_miny, __float_as_uint(p.y));
        atomicMax(&s_maxh, __float_as_uint(h));
    }
    __syncthreads();
    if (t == 0) {
        bMinX[b] = __uint_as_float(s_minx);
        bMinY[b] = __uint_as_float(s_miny);
        bMaxH[b] = __uint_as_float(s_maxh);
    }
    grid.sync();

    // ---- P1: combine 256 partials (redundant per block; min/max exact and
    //          order-independent -> identical in every block) + bin
    if (t == 0) { s_minx = 0x7f7fffffu; s_miny = 0x7f7fffffu; s_maxh = 0u; }
    __syncthreads();
    if (t < 256) {
        atomicMin(&s_minx, __float_as_uint(bMinX[t]));
        atomicMin(&s_miny, __float_as_uint(bMinY[t]));
        atomicMax(&s_maxh, __float_as_uint(bMaxH[t]));
    }
    __syncthreads();
    {
        float hmax  = __uint_as_float(s_maxh);
        float qminx = __uint_as_float(s_minx) - hmax;
        float qminy = __uint_as_float(s_miny) - hmax;
        float2 p = pos2[tid];
        int cx = (int)ceilf((p.x - qminx) / hmax);
        int cy = (int)ceilf((p.y - qminy) / hmax);
        cx = min(max(cx, 0), GRID_DIM - 1);
        cy = min(max(cy, 0), GRID_DIM - 1);
        int l = cx + GRID_DIM * cy;
        lin[tid] = l;
        atomicAdd(&counts[l], 1);
    }
    grid.sync();

    // ---- P2: each block scans its 256-cell chunk (t<256 active; barriers
    //          executed by ALL threads) ----
    {
        int v = 0;
        if (t < 256) { v = counts[b * 256 + t]; sd[t] = v; }
        __syncthreads();
#pragma unroll
        for (int off = 1; off < 256; off <<= 1) {
            int x = (t < 256 && t >= off) ? sd[t - off] : 0;
            __syncthreads();
            if (t < 256) sd[t] += x;
            __syncthreads();
        }
        if (t < 256) starts[b * 256 + t] = sd[t] - v;   // exclusive in chunk
        if (t == 255) chunkSums[b] = sd[255];
    }
    grid.sync();

    // ---- P3: every block redundantly scans the 256 chunk sums, applies ----
    {
        int cv = 0;
        if (t < 256) { cv = chunkSums[t]; sd[t] = cv; }
        __syncthreads();
#pragma unroll
        for (int off = 1; off < 256; off <<= 1) {
            int x = (t < 256 && t >= off) ? sd[t - off] : 0;
            __syncthreads();
            if (t < 256) sd[t] += x;
            __syncthreads();
        }
        int offB = (b == 0) ? 0 : sd[b - 1];
        if (t < 256) starts[b * 256 + t] += offB;
        if (tid == 0) {
            starts[NUM_CELLS]     = N_PART;   // reference overflow row: empty
            starts[NUM_CELLS + 1] = N_PART;
        }
    }
    grid.sync();

    // ---- P4: scatter (arbitrary intra-cell order; ordered at emit) ----
    {
        int c = lin[tid];
        int r = atomicAdd(&cursor[c], 1);
        sid[starts[c] + r] = tid;
    }
    grid.sync();

    // ---- P5: per-particle ordered emit: rank = #(smaller ids in my cell)
    //          restores ascending-id order (stable argsort semantics).
    //          e~Poisson(4) sequential sid reads; pos2/sup loads coalesced.
    {
        int c  = lin[tid];
        int bb = starts[c], ee = starts[c + 1];
        int rank = 0;
        for (int s = bb; s < ee; s++) rank += (sid[s] < tid);
        float2 p = pos2[tid];           // bitwise copy: query numerics identical
        Q[bb + rank]    = make_float4(p.x, p.y, __int_as_float(tid), sup[tid]);
        linS[bb + rank] = c;
    }
}

// One wave per RANK (cell-sorted order): consecutive waves read overlapping
// dense CSR segments -> L1/L2 hits. Bijective XCD swizzle (gridDim 65536
// divisible by 8) gives each XCD a contiguous 1/8 of the rank range, so its
// private L2 holds ~0.5MB of Q instead of all 4MB. Wave-uniform state in
// SGPRs via readfirstlane. The reference's boundary decision
// RN(sqrt(s2)) <= h is an interval of f32 s2 values, so it collapses to ONE
// v_cmp_le_f32 against S = largest f32 < mid^2, mid = (h+nextafterf(h))/2
// (mid^2 exact in double, 50 bits; never a 24-bit f32 -> no ties). sqrt only
// once per stored lane in the epilogue: v_sqrt_f32 * v_rcp_f32 (~3ulp, well
// inside the comparator tolerance; absmax 0.0039 passed rounds 1-2).
__global__ __launch_bounds__(256) void query_kernel(
        const int* __restrict__ linS, const float4* __restrict__ Q,
        const int* __restrict__ starts,
        float* __restrict__ outN, float* __restrict__ outC,
        float* __restrict__ outR, int n) {
#pragma clang fp contract(off)
    __shared__ int   s_id[4][MAXNB];
    __shared__ float s_s2[4][MAXNB];

    int bid = blockIdx.x;
    int swz = (bid & 7) * (int)(gridDim.x >> 3) + (bid >> 3);   // bijective
    int gtid = swz * 256 + threadIdx.x;
    int r    = gtid >> 6;              // rank in cell-sorted order (grid exact)
    int lane = threadIdx.x & 63;
    int wsl  = threadIdx.x >> 6;

    float4 me = Q[r];
    int   i  = __builtin_amdgcn_readfirstlane(__float_as_int(me.z));
    float px = __int_as_float(__builtin_amdgcn_readfirstlane(__float_as_int(me.x)));
    float py = __int_as_float(__builtin_amdgcn_readfirstlane(__float_as_int(me.y)));
    float h  = __int_as_float(__builtin_amdgcn_readfirstlane(__float_as_int(me.w)));
    int   L  = __builtin_amdgcn_readfirstlane(linS[r]);

    // exact f32 threshold for RN(sqrt(s2)) <= h   (h > 0, normal)
    float  hn  = __int_as_float(__float_as_int(h) + 1);     // nextafter(h, inf)
    double mid = 0.5 * ((double)h + (double)hn);
    double t2  = mid * mid;                                  // exact (50 bits)
    float  S   = (float)t2;                                  // RN
    S = ((double)S > t2) ? __int_as_float(__float_as_int(S) - 1) : S;  // RD

    // reference candidate-cell order: offs = dx + 256*dy, ij-meshgrid
    const int offs[9] = {-257, -1, 255, -256, 0, 256, -255, 1, 257};
    int cum[10], delta[9];
    cum[0] = 0;
#pragma unroll
    for (int o = 0; o < 9; o++) {
        int cell = L + offs[o];
        cell = min(max(cell, 0), NUM_CELLS);   // clip (duplicates at edges,
                                               //  exactly like the reference)
        int bb = __builtin_amdgcn_readfirstlane(starts[cell]);
        int ee = __builtin_amdgcn_readfirstlane(starts[cell + 1]);
        int cc = min(ee - bb, KSLOT);          // keep lowest-32 ids, as ref
        delta[o]  = bb - cum[o];               // idx = ll + delta[seg]
        cum[o + 1] = cum[o] + cc;
    }
    int T = cum[9];

    int total = 0;
    for (int b0 = 0; b0 < T; b0 += 64) {
        int ll = b0 + lane;
        int dsel = delta[0];
#pragma unroll
        for (int m = 1; m < 9; m++)
            dsel = (ll >= cum[m]) ? delta[m] : dsel;
        int idx = ll + dsel;                   // <= N+63: Q padded by 64
        float4 q = Q[idx];
        float dx = q.x - px;
        float dy = q.y - py;
        float s2 = dx * dx + dy * dy;          // contract(off): match XLA
        // scalar tail mask (SALU): lanes with ll >= T
        int rem = T - b0;
        unsigned long long maskT =
            (rem >= 64) ? ~0ull : ((1ull << rem) - 1ull);
        unsigned long long bal = __ballot(s2 <= S) & maskT;
        int rank = __builtin_amdgcn_mbcnt_hi(
            (unsigned)(bal >> 32),
            __builtin_amdgcn_mbcnt_lo((unsigned)bal, 0));
        int w = total + rank;
        if ((s2 <= S) && (ll < T) && (w < MAXNB)) {
            s_id[wsl][w] = __float_as_int(q.z);
            s_s2[wsl][w] = s2;
        }
        total += (int)__popcll(bal);
    }

    // wave-private LDS buffer, same-wave DS ops are ordered: no barrier.
    int stored = min(total, MAXNB);
    float rh = __builtin_amdgcn_rcpf(h);       // 1ulp; tolerance-covered
    size_t base = (size_t)i * MAXNB;           // 256B-aligned, fully written
    int   jj = s_id[wsl][lane];                // garbage beyond 'stored' is
    float ss = s_s2[wsl][lane];                //  discarded by cndmask below
    bool inb = lane < stored;
    float vN = inb ? (float)jj : -1.0f;
    float vR = inb ? __builtin_amdgcn_sqrtf(ss) * rh : 0.0f;
    outN[base + lane] = vN;
    outR[base + lane] = vR;
    if (lane == 0) outC[i] = (float)total;
}

extern "C" void kernel_launch(void* const* d_in, const int* in_sizes, int n_in,
                              void* d_out, int out_size, void* d_ws, size_t ws_size,
                              hipStream_t stream) {
    const float2* pos2 = (const float2*)d_in[0];
    const float*  sup  = (const float*)d_in[1];

    char* p = (char*)d_ws;
    auto alloc = [&](size_t bytes) {
        char* q = p;
        p += (bytes + 255) & ~(size_t)255;
        return q;
    };
    int*    counts    = (int*)alloc((size_t)NUM_CELLS * 4);
    int*    cursor    = (int*)alloc((size_t)NUM_CELLS * 4);
    int*    chunkSums = (int*)alloc(256 * 4);
    int*    starts    = (int*)alloc((size_t)(NUM_CELLS + 2) * 4);
    int*    lin       = (int*)alloc((size_t)N_PART * 4);
    int*    sid       = (int*)alloc((size_t)(N_PART + 64) * 4);
    int*    linS      = (int*)alloc((size_t)N_PART * 4);
    float4* Q         = (float4*)alloc((size_t)(N_PART + 64) * 16);
    float*  bMinX     = (float*)alloc(256 * 4);
    float*  bMinY     = (float*)alloc(256 * 4);
    float*  bMaxH     = (float*)alloc(256 * 4);

    float* out  = (float*)d_out;
    float* outN = out;                              // N*64 neighbor ids (as f32)
    float* outC = out + (size_t)N_PART * MAXNB;     // N counts
    float* outR = outC + N_PART;                    // N*64 radial

    void* args[] = { (void*)&pos2, (void*)&sup, (void*)&counts, (void*)&cursor,
                     (void*)&chunkSums, (void*)&starts, (void*)&lin,
                     (void*)&sid, (void*)&linS, (void*)&Q,
                     (void*)&bMinX, (void*)&bMinY, (void*)&bMaxH };
    hipLaunchCooperativeKernel((const void*)build_kernel, dim3(BLD_BLOCKS),
                               dim3(BLD_TPB), args, 0, stream);
    // one wave per rank: N_PART waves = N_PART*64 threads
    query_kernel<<<(N_PART * 64) / 256, 256, 0, stream>>>(
        linS, Q, starts, outN, outC, outR, N_PART);
}

// Round 6
// 272.165 us; speedup vs baseline: 1.6529x; 1.4809x over previous
//
#include <hip/hip_runtime.h>
#include <float.h>

#define N_PART 262144
#define GRID_DIM 256
#define NUM_CELLS (GRID_DIM * GRID_DIM)
#define KP 32                          // padded slots per cell (= reference K)
#define MAXNB 64

// ---------------- ws layout (all 256B-aligned) ----------------
// counts : NUM_CELLS+1 ints   (zeroed in D1; [NUM_CELLS] stays 0 = clip row)
// bMinX/Y/H : 1024 floats each (per-block reduce partials)
// lin    : N ints             (cell of each particle)
// tableA : (NUM_CELLS+1)*KP ints   (raw ids, arrival order)
// Qpad   : (NUM_CELLS+1)*KP + 64 float4  ({x, y, id-bits, S}, id-sorted)
//
// Sync-point economics (r3/r5 lesson): a grid.sync() costs ~ a dispatch
// boundary (~25-35us); cooperative fusion saves nothing. So: FOUR ordinary
// dispatches, each full-occupancy, no scan/scatter/sort passes.

__global__ __launch_bounds__(256) void prep_kernel(
        const float2* __restrict__ pos2, const float* __restrict__ sup,
        int* __restrict__ counts,
        float* __restrict__ bMinX, float* __restrict__ bMinY,
        float* __restrict__ bMaxH) {
    __shared__ unsigned s_minx, s_miny, s_maxh;
    int t = threadIdx.x, b = blockIdx.x;
    int tid = b * 256 + t;
    if (tid <= NUM_CELLS) counts[tid] = 0;
    if (t == 0) { s_minx = 0x7f7fffffu; s_miny = 0x7f7fffffu; s_maxh = 0u; }
    __syncthreads();
    float2 p = pos2[tid];
    float  h = sup[tid];
    // non-negative floats: uint compare == float compare
    atomicMin(&s_minx, __float_as_uint(p.x));
    atomicMin(&s_miny, __float_as_uint(p.y));
    atomicMax(&s_maxh, __float_as_uint(h));
    __syncthreads();
    if (t == 0) {
        bMinX[b] = __uint_as_float(s_minx);
        bMinY[b] = __uint_as_float(s_miny);
        bMaxH[b] = __uint_as_float(s_maxh);
    }
}

__global__ __launch_bounds__(256) void bin_kernel(
        const float2* __restrict__ pos2,
        const float* __restrict__ bMinX, const float* __restrict__ bMinY,
        const float* __restrict__ bMaxH,
        int* __restrict__ counts, int* __restrict__ tableA,
        int* __restrict__ lin) {
    __shared__ unsigned s_minx, s_miny, s_maxh;
    int t = threadIdx.x;
    int tid = blockIdx.x * 256 + t;
    // redundant per-block combine of 1024 partials: min/max exact and
    // order-independent -> identical result in every block
    if (t == 0) { s_minx = 0x7f7fffffu; s_miny = 0x7f7fffffu; s_maxh = 0u; }
    __syncthreads();
    {
        float mx = FLT_MAX, my = FLT_MAX, mh = 0.0f;
        for (int k = t; k < 1024; k += 256) {
            mx = fminf(mx, bMinX[k]);
            my = fminf(my, bMinY[k]);
            mh = fmaxf(mh, bMaxH[k]);
        }
        atomicMin(&s_minx, __float_as_uint(mx));
        atomicMin(&s_miny, __float_as_uint(my));
        atomicMax(&s_maxh, __float_as_uint(mh));
    }
    __syncthreads();
    float hmax  = __uint_as_float(s_maxh);
    float qminx = __uint_as_float(s_minx) - hmax;
    float qminy = __uint_as_float(s_miny) - hmax;
    float2 p = pos2[tid];
    int cx = (int)ceilf((p.x - qminx) / hmax);
    int cy = (int)ceilf((p.y - qminy) / hmax);
    cx = min(max(cx, 0), GRID_DIM - 1);
    cy = min(max(cy, 0), GRID_DIM - 1);
    int c = cx + GRID_DIM * cy;
    lin[tid] = c;
    int slot = atomicAdd(&counts[c], 1);
    if (slot < KP) tableA[(c << 5) + slot] = tid;   // Poisson(4): never >32
}

// per particle: rank = #(smaller ids in my cell row) -> write the packed
// record at its FINAL id-sorted position (stable argsort semantics).
// Replaces scan+scatter+sort with one full-occupancy pass. Also precompute
// S = the exact f32 threshold with  s2 <= S  <=>  RN(sqrt(s2)) <= h :
// mid = (h + nextafterf(h))/2; mid^2 exact in double (50 bits) and never a
// 24-bit f32 -> no ties; S = largest f32 <= mid^2 rounded down.
__global__ __launch_bounds__(256) void rank_kernel(
        const float2* __restrict__ pos2, const float* __restrict__ sup,
        const int* __restrict__ counts, const int* __restrict__ tableA,
        const int* __restrict__ lin, float4* __restrict__ Qpad) {
    int tid = blockIdx.x * 256 + threadIdx.x;
    int c   = lin[tid];
    int cnt = min(counts[c], KP);
    const int* row = tableA + (c << 5);
    int rank = 0;
    for (int k = 0; k < cnt; k++) rank += (row[k] < tid);
    float2 p = pos2[tid];               // bitwise copy: query numerics identical
    float  h = sup[tid];
    float  hn  = __int_as_float(__float_as_int(h) + 1);     // nextafter(h,inf)
    double mid = 0.5 * ((double)h + (double)hn);
    double t2  = mid * mid;                                  // exact
    float  S   = (float)t2;                                  // RN
    S = ((double)S > t2) ? __int_as_float(__float_as_int(S) - 1) : S;
    Qpad[(c << 5) + rank] = make_float4(p.x, p.y, __int_as_float(tid), S);
}

// One wave per CELL: the 9-cell cum/delta setup is amortized over the
// cell's e~4 particles, and (T<=64 fast path, ~all cells) the candidate
// records are loaded ONCE per cell and reused -- the particle's own record
// comes from v_readlane, zero loads. Candidate order = reference order:
// cells by offs (clip duplicates at edges included), within cell ascending
// id (Qpad is rank-sorted). Compaction by masked ballot + mbcnt. Epilogue
// per particle writes its fully-covered 256B output rows.
__global__ __launch_bounds__(256) void query_kernel(
        const int* __restrict__ counts, const float4* __restrict__ Qpad,
        float* __restrict__ outN, float* __restrict__ outC,
        float* __restrict__ outR) {
#pragma clang fp contract(off)
    __shared__ int   s_id[4][MAXNB];
    __shared__ float s_s2[4][MAXNB];

    int t    = threadIdx.x;
    int lane = t & 63;
    int wsl  = t >> 6;
    int bid  = blockIdx.x;
    int swz  = (bid & 7) * (int)(gridDim.x >> 3) + (bid >> 3);  // bijective XCD
    int cell = __builtin_amdgcn_readfirstlane(swz * 4 + wsl);

    const int offs[9] = {-257, -1, 255, -256, 0, 256, -255, 1, 257};
    int cum[10], delta[9];
    cum[0] = 0;
#pragma unroll
    for (int o = 0; o < 9; o++) {
        int cl = min(max(cell + offs[o], 0), NUM_CELLS);  // clip, dups at edges
        int cc = min(__builtin_amdgcn_readfirstlane(counts[cl]), KP);
        delta[o]   = (cl << 5) - cum[o];                  // idx = ll + delta[o]
        cum[o + 1] = cum[o] + cc;
    }
    int T   = cum[9];
    int cnt = cum[5] - cum[4];          // center-cell count (= my particles)
    if (cnt == 0) return;               // no LDS/barrier deps: safe early-out

    if (T <= 64) {
        // ---- fast path: one candidate per lane, cached in registers ----
        int dsel = delta[0];
#pragma unroll
        for (int m = 1; m < 9; m++)
            dsel = (lane >= cum[m]) ? delta[m] : dsel;
        float4 q = Qpad[lane + dsel];   // rows beyond cnt: garbage, masked off
        unsigned long long maskT = (T >= 64) ? ~0ull : ((1ull << T) - 1ull);
        for (int s = 0; s < cnt; s++) {
            int src = cum[4] + s;       // lane holding my particle's record
            float px = __int_as_float(__builtin_amdgcn_readlane(__float_as_int(q.x), src));
            float py = __int_as_float(__builtin_amdgcn_readlane(__float_as_int(q.y), src));
            int   ib = __builtin_amdgcn_readlane(__float_as_int(q.z), src);
            float S  = __int_as_float(__builtin_amdgcn_readlane(__float_as_int(q.w), src));
            float dx = q.x - px;
            float dy = q.y - py;
            float s2 = dx * dx + dy * dy;          // contract(off): match XLA
            bool keep = (s2 <= S) && (lane < T);   // garbage lanes masked
            unsigned long long bal = __ballot(s2 <= S) & maskT;
            int rank = __builtin_amdgcn_mbcnt_hi(
                (unsigned)(bal >> 32),
                __builtin_amdgcn_mbcnt_lo((unsigned)bal, 0));
            if (keep) {                            // T<=64 -> rank < 64 always
                s_id[wsl][rank] = __float_as_int(q.z);
                s_s2[wsl][rank] = s2;
            }
            int total = (int)__popcll(bal);
            // wave-private LDS, same-wave DS ops ordered: no barrier. Stale
            // entries beyond 'total' discarded by the inb select.
            int   jj = s_id[wsl][lane];
            float ss = s_s2[wsl][lane];
            bool inb = lane < total;
            float rh = __builtin_amdgcn_rsqf(S);   // ~1/h, 1ulp; tol-covered
            float vN = inb ? (float)jj : -1.0f;
            float vR = inb ? __builtin_amdgcn_sqrtf(ss) * rh : 0.0f;
            size_t base = (size_t)ib * MAXNB;      // 256B row, fully written
            outN[base + lane] = vN;
            outR[base + lane] = vR;
            if (lane == 0) outC[ib] = (float)total;
        }
    } else {
        // ---- rare path (P(T>64) ~ 1e-5 per cell): batched, re-loads ----
        for (int s = 0; s < cnt; s++) {
            float4 me = Qpad[(cell << 5) + s];
            int   ib = __builtin_amdgcn_readfirstlane(__float_as_int(me.z));
            float px = __int_as_float(__builtin_amdgcn_readfirstlane(__float_as_int(me.x)));
            float py = __int_as_float(__builtin_amdgcn_readfirstlane(__float_as_int(me.y)));
            float S  = __int_as_float(__builtin_amdgcn_readfirstlane(__float_as_int(me.w)));
            int total = 0;
            for (int b0 = 0; b0 < T; b0 += 64) {
                int ll = b0 + lane;
                int dsel = delta[0];
#pragma unroll
                for (int m = 1; m < 9; m++)
                    dsel = (ll >= cum[m]) ? delta[m] : dsel;
                float4 q = Qpad[ll + dsel];
                float dx = q.x - px;
                float dy = q.y - py;
                float s2 = dx * dx + dy * dy;
                int rem = T - b0;
                unsigned long long maskT =
                    (rem >= 64) ? ~0ull : ((1ull << rem) - 1ull);
                unsigned long long bal = __ballot(s2 <= S) & maskT;
                int rank = __builtin_amdgcn_mbcnt_hi(
                    (unsigned)(bal >> 32),
                    __builtin_amdgcn_mbcnt_lo((unsigned)bal, 0));
                int w = total + rank;
                if ((s2 <= S) && (ll < T) && (w < MAXNB)) {
                    s_id[wsl][w] = __float_as_int(q.z);
                    s_s2[wsl][w] = s2;
                }
                total += (int)__popcll(bal);
            }
            int stored = min(total, MAXNB);
            int   jj = s_id[wsl][lane];
            float ss = s_s2[wsl][lane];
            bool inb = lane < stored;
            float rh = __builtin_amdgcn_rsqf(S);
            float vN = inb ? (float)jj : -1.0f;
            float vR = inb ? __builtin_amdgcn_sqrtf(ss) * rh : 0.0f;
            size_t base = (size_t)ib * MAXNB;
            outN[base + lane] = vN;
            outR[base + lane] = vR;
            if (lane == 0) outC[ib] = (float)total;
        }
    }
}

extern "C" void kernel_launch(void* const* d_in, const int* in_sizes, int n_in,
                              void* d_out, int out_size, void* d_ws, size_t ws_size,
                              hipStream_t stream) {
    const float2* pos2 = (const float2*)d_in[0];
    const float*  sup  = (const float*)d_in[1];

    char* p = (char*)d_ws;
    auto alloc = [&](size_t bytes) {
        char* q = p;
        p += (bytes + 255) & ~(size_t)255;
        return q;
    };
    int*    counts = (int*)alloc((size_t)(NUM_CELLS + 1) * 4);
    float*  bMinX  = (float*)alloc(1024 * 4);
    float*  bMinY  = (float*)alloc(1024 * 4);
    float*  bMaxH  = (float*)alloc(1024 * 4);
    int*    lin    = (int*)alloc((size_t)N_PART * 4);
    int*    tableA = (int*)alloc((size_t)(NUM_CELLS + 1) * KP * 4);
    float4* Qpad   = (float4*)alloc(((size_t)(NUM_CELLS + 1) * KP + 64) * 16);

    float* out  = (float*)d_out;
    float* outN = out;                              // N*64 neighbor ids (as f32)
    float* outC = out + (size_t)N_PART * MAXNB;     // N counts
    float* outR = outC + N_PART;                    // N*64 radial

    prep_kernel<<<N_PART / 256, 256, 0, stream>>>(pos2, sup, counts,
                                                  bMinX, bMinY, bMaxH);
    bin_kernel<<<N_PART / 256, 256, 0, stream>>>(pos2, bMinX, bMinY, bMaxH,
                                                 counts, tableA, lin);
    rank_kernel<<<N_PART / 256, 256, 0, stream>>>(pos2, sup, counts, tableA,
                                                  lin, Qpad);
    // one wave per cell: NUM_CELLS waves, 4 cells per 256-thread block
    query_kernel<<<NUM_CELLS / 4, 256, 0, stream>>>(counts, Qpad,
                                                    outN, outC, outR);
}